// Round 5
// baseline (212.187 us; speedup 1.0000x reference)
//
#include <hip/hip_runtime.h>
#include <math.h>

#define B_G   256
#define IN_D  128
#define FD    256
#define HID   256
#define OUT_D 128
#define TXT   512

typedef short bf16x8 __attribute__((ext_vector_type(8)));
typedef float f32x4  __attribute__((ext_vector_type(4)));

// ---------------------------------------------------------------------------
// bf16 helpers (RNE)
// ---------------------------------------------------------------------------
__device__ __forceinline__ unsigned bf_rne(float x) {
    unsigned u = __float_as_uint(x);
    u += 0x7fffu + ((u >> 16) & 1u);
    return u >> 16;
}
__device__ __forceinline__ float bf_to_f(unsigned h) {
    return __uint_as_float(h << 16);
}
// pack 8 floats -> hi bf16x8 (A-side uses hi only; error attenuates via softmax)
__device__ __forceinline__ bf16x8 pack_hi8(const float4& v0, const float4& v1) {
    uint4 h;
    h.x = bf_rne(v0.x) | (bf_rne(v0.y) << 16);
    h.y = bf_rne(v0.z) | (bf_rne(v0.w) << 16);
    h.z = bf_rne(v1.x) | (bf_rne(v1.y) << 16);
    h.w = bf_rne(v1.z) | (bf_rne(v1.w) << 16);
    return __builtin_bit_cast(bf16x8, h);
}

// ---------------------------------------------------------------------------
// Kernel A (grid 259 x 1024): fused prep.
//  blocks 0..255  : q_b = te@Wq+bq ; qk_b = Wk@q_b ; zero hsum[b]
//                   (k-dim split 4x across thread groups -> short chains)
//  blocks 256..257: split W0/W2 into fragment-layout hi/lo bf16 buffers
//  block  258     : parallel scan of lens -> offsets
// ---------------------------------------------------------------------------
__global__ __launch_bounds__(1024) void k_prepA(
    const float* __restrict__ text_emb, const float* __restrict__ Wq,
    const float* __restrict__ bq, const float* __restrict__ Wk,
    const float* __restrict__ W0, const float* __restrict__ W2,
    const int* __restrict__ lens,
    float* __restrict__ qk, int* __restrict__ offsets, float* __restrict__ hsum,
    unsigned short* __restrict__ W0sH, unsigned short* __restrict__ W0sL,
    unsigned short* __restrict__ W2sH, unsigned short* __restrict__ W2sL)
{
    int blk = blockIdx.x, tid = threadIdx.x;
    int t = tid & 255, g = tid >> 8;
    __shared__ float te[TXT];
    __shared__ float qsh[FD];
    __shared__ float part[4][FD];
    __shared__ int   sc[B_G];

    if (blk < 256) {
        int b = blk;
        if (g == 0) hsum[b * FD + t] = 0.f;
        if (tid < TXT) te[tid] = text_emb[(size_t)b * TXT + tid];
        __syncthreads();
        // q partial: k-range [128g, 128g+128)
        float acc = (g == 0) ? bq[t] : 0.f;
        const float* Wqp = Wq + (size_t)(128 * g) * FD + t;
        for (int k = 0; k < 128; k++) acc = fmaf(te[128 * g + k], Wqp[(size_t)k * FD], acc);
        part[g][t] = acc;
        __syncthreads();
        if (g == 0) qsh[t] = part[0][t] + part[1][t] + part[2][t] + part[3][t];
        __syncthreads();
        // qk partial: f-range [64g, 64g+64)
        float a2 = 0.f;
        for (int f = 64 * g; f < 64 * g + 64; f++) a2 = fmaf(Wk[(size_t)t * FD + f], qsh[f], a2);
        part[g][t] = a2;
        __syncthreads();
        if (g == 0) qk[b * FD + t] = part[0][t] + part[1][t] + part[2][t] + part[3][t];
    } else if (blk < 258) {
        int e = (blk - 256) * 1024 + tid;   // 0..2047
        if (e < 1024) {
            int kc = e >> 8, c = e & 255;
            size_t base = (size_t)(kc * 256 + c) * 32;
            for (int kk = 0; kk < 32; kk++) {
                float v = W0[(size_t)(kc * 32 + kk) * FD + c];
                unsigned h = bf_rne(v);
                float r = v - bf_to_f(h);
                W0sH[base + kk] = (unsigned short)h;
                W0sL[base + kk] = (unsigned short)bf_rne(r);
            }
        } else {
            int e2 = e - 1024;
            int kc = e2 >> 7, c = e2 & 127;
            size_t base = (size_t)(kc * 128 + c) * 32;
            for (int kk = 0; kk < 32; kk++) {
                float v = W2[(size_t)(kc * 32 + kk) * OUT_D + c];
                unsigned h = bf_rne(v);
                float r = v - bf_to_f(h);
                W2sH[base + kk] = (unsigned short)h;
                W2sL[base + kk] = (unsigned short)bf_rne(r);
            }
        }
    } else {
        if (tid < 256) sc[tid] = lens[tid];
        __syncthreads();
        for (int d = 1; d < 256; d <<= 1) {
            int v = (tid < 256 && tid >= d) ? sc[tid - d] : 0;
            __syncthreads();
            if (tid < 256) sc[tid] += v;
            __syncthreads();
        }
        if (tid < 256) offsets[tid + 1] = sc[tid];
        if (tid == 0) offsets[0] = 0;
    }
}

// ---------------------------------------------------------------------------
// K1: software-pipelined MFMA.  A = bf16(X) (hi only), B = W0 hi+lo.
// A(kc+1) prefetched into registers while kc's MFMAs run; B loaded at
// iteration top (L2-hot), latency covered by the A-split VALU.
// ---------------------------------------------------------------------------
__global__ __launch_bounds__(256, 2) void k_l0_mfma(
    const float* __restrict__ X,
    const unsigned short* __restrict__ W0sH, const unsigned short* __restrict__ W0sL,
    const float* __restrict__ b0, const float* __restrict__ qk,
    const int* __restrict__ offsets,
    float* __restrict__ scores, float* __restrict__ hsum)
{
    int b = blockIdx.y;
    int off = offsets[b], len = offsets[b + 1] - off;
    int n0 = blockIdx.x * 64;
    if (n0 >= len) return;
    int nvalid = min(64, len - n0);

    __shared__ float qks[FD];
    __shared__ float bsh[FD];
    __shared__ float red[4][64];

    int tid = threadIdx.x;
    int lane = tid & 63, w = tid >> 6;
    int ln = lane & 15, quad = lane >> 4;

    qks[tid] = qk[b * FD + tid];
    bsh[tid] = b0[tid];

    // per-lane A row pointers (lane's quad owns bytes [kc*128 + quad*32, +32))
    const float* Xbase = X + (size_t)(off + n0) * IN_D;
    const float* arow[4];
    bool aval[4];
#pragma unroll
    for (int i = 0; i < 4; i++) {
        int node = 16 * i + ln;
        aval[i] = node < nvalid;
        arow[i] = Xbase + (size_t)(aval[i] ? node : 0) * IN_D + quad * 8;
    }
    // per-lane B fragment pointers (c-offset fixed; kc adds 256*32 elements)
    const unsigned short* bph[4];
    const unsigned short* bpl[4];
#pragma unroll
    for (int j = 0; j < 4; j++) {
        int c = 64 * w + 16 * j + ln;
        bph[j] = W0sH + (size_t)c * 32 + quad * 8;
        bpl[j] = W0sL + (size_t)c * 32 + quad * 8;
    }

    f32x4 acc[4][4] = {};
    float4 aC[4][2];
    // prologue: A(0)
#pragma unroll
    for (int i = 0; i < 4; i++) {
        const float4* p = (const float4*)(arow[i]);
        aC[i][0] = p[0]; aC[i][1] = p[1];
    }

#pragma unroll
    for (int kc = 0; kc < 4; kc++) {
        float4 aN[4][2];
        if (kc < 3) {
#pragma unroll
            for (int i = 0; i < 4; i++) {
                const float4* p = (const float4*)(arow[i] + (kc + 1) * 32);
                aN[i][0] = p[0]; aN[i][1] = p[1];
            }
        }
        // B loads for this kc (L2-hot)
        uint4 bh[4], bl[4];
#pragma unroll
        for (int j = 0; j < 4; j++) {
            bh[j] = *(const uint4*)(bph[j] + (size_t)kc * 8192);
            bl[j] = *(const uint4*)(bpl[j] + (size_t)kc * 8192);
        }
        // split A(kc) -> hi fragments (zero masked rows)
        bf16x8 AH[4];
#pragma unroll
        for (int i = 0; i < 4; i++) {
            float4 v0 = aC[i][0], v1 = aC[i][1];
            if (!aval[i]) { v0 = make_float4(0, 0, 0, 0); v1 = v0; }
            AH[i] = pack_hi8(v0, v1);
        }
#pragma unroll
        for (int i = 0; i < 4; i++)
#pragma unroll
            for (int j = 0; j < 4; j++) {
                acc[i][j] = __builtin_amdgcn_mfma_f32_16x16x32_bf16(
                    AH[i], __builtin_bit_cast(bf16x8, bh[j]), acc[i][j], 0, 0, 0);
                acc[i][j] = __builtin_amdgcn_mfma_f32_16x16x32_bf16(
                    AH[i], __builtin_bit_cast(bf16x8, bl[j]), acc[i][j], 0, 0, 0);
            }
        if (kc < 3) {
#pragma unroll
            for (int i = 0; i < 4; i++) { aC[i][0] = aN[i][0]; aC[i][1] = aN[i][1]; }
        }
    }
    __syncthreads();   // qks/bsh visible for epilogue

    // ---- epilogue: bias+relu+mask -> score partials & column sums ----
    float sp[4][4];
    float cs[4] = {0.f, 0.f, 0.f, 0.f};
#pragma unroll
    for (int i = 0; i < 4; i++)
#pragma unroll
        for (int r = 0; r < 4; r++) sp[i][r] = 0.f;

#pragma unroll
    for (int i = 0; i < 4; i++)
#pragma unroll
        for (int j = 0; j < 4; j++) {
            int c = 64 * w + 16 * j + ln;
            float bb = bsh[c], qv = qks[c];
#pragma unroll
            for (int r = 0; r < 4; r++) {
                int node = 16 * i + 4 * quad + r;
                float h = acc[i][j][r] + bb;
                h = (h > 0.f && node < nvalid) ? h : 0.f;
                sp[i][r] = fmaf(h, qv, sp[i][r]);
                cs[j] += h;
            }
        }
#pragma unroll
    for (int i = 0; i < 4; i++)
#pragma unroll
        for (int r = 0; r < 4; r++) {
            float s = sp[i][r];
            s += __shfl_xor(s, 1); s += __shfl_xor(s, 2);
            s += __shfl_xor(s, 4); s += __shfl_xor(s, 8);
            sp[i][r] = s;
        }
    if (ln == 0) {
#pragma unroll
        for (int i = 0; i < 4; i++)
#pragma unroll
            for (int r = 0; r < 4; r++)
                red[w][16 * i + 4 * quad + r] = sp[i][r];
    }
#pragma unroll
    for (int j = 0; j < 4; j++) {
        float s = cs[j];
        s += __shfl_xor(s, 16); s += __shfl_xor(s, 32);
        if (quad == 0) atomicAdd(&hsum[b * FD + 64 * w + 16 * j + ln], s);
    }
    __syncthreads();
    if (tid < 64 && tid < nvalid)
        scores[off + n0 + tid] = red[0][tid] + red[1][tid] + red[2][tid] + red[3][tid];
}

// ---------------------------------------------------------------------------
// K2: per-graph softmax stats + w_b = (hsum_b @ Wv + len*bv) @ Wo
// ---------------------------------------------------------------------------
__global__ __launch_bounds__(1024) void k_graph(
    const float* __restrict__ scores, const float* __restrict__ hsum,
    const float* __restrict__ Wv, const float* __restrict__ bv,
    const float* __restrict__ Wo, const int* __restrict__ offsets,
    float* __restrict__ wvec, float* __restrict__ smax, float* __restrict__ dinv)
{
    int b = blockIdx.x, tid = threadIdx.x;
    int t = tid & 255, g = tid >> 8;
    int off = offsets[b], len = offsets[b + 1] - off;
    __shared__ float redm[16], reds[16];
    __shared__ float hs[FD], vs[FD];
    __shared__ float part[4][FD];

    float m = -INFINITY;
    for (int i = tid; i < len; i += 1024) m = fmaxf(m, scores[off + i]);
    for (int d = 1; d < 64; d <<= 1) m = fmaxf(m, __shfl_xor(m, d));
    if ((tid & 63) == 0) redm[tid >> 6] = m;
    __syncthreads();
    m = -INFINITY;
#pragma unroll
    for (int k = 0; k < 16; k++) m = fmaxf(m, redm[k]);

    float s = 0.f;
    for (int i = tid; i < len; i += 1024) s += expf(scores[off + i] - m);
    for (int d = 1; d < 64; d <<= 1) s += __shfl_xor(s, d);
    if ((tid & 63) == 0) reds[tid >> 6] = s;
    if (g == 0) hs[t] = hsum[b * FD + t];
    __syncthreads();
    s = 0.f;
#pragma unroll
    for (int k = 0; k < 16; k++) s += reds[k];

    float acc = (g == 0) ? (float)len * bv[t] : 0.f;
    for (int f = 64 * g; f < 64 * g + 64; f++) acc = fmaf(hs[f], Wv[f * FD + t], acc);
    part[g][t] = acc;
    __syncthreads();
    if (g == 0) vs[t] = part[0][t] + part[1][t] + part[2][t] + part[3][t];
    __syncthreads();
    float a2 = 0.f;
    for (int f = 64 * g; f < 64 * g + 64; f++) a2 = fmaf(vs[f], Wo[f * HID + t], a2);
    part[g][t] = a2;
    __syncthreads();
    if (g == 0) wvec[b * HID + t] = part[0][t] + part[1][t] + part[2][t] + part[3][t];
    if (tid == 0) { smax[b] = m; dinv[b] = 1.0f / s; }
}

// ---------------------------------------------------------------------------
// K3: software-pipelined MFMA.  A = bf16(Z) (hi only, computed in-reg),
// B = W2 hi+lo double-buffered across kc.
// ---------------------------------------------------------------------------
__global__ __launch_bounds__(256, 2) void k_fin_mfma(
    const float* __restrict__ scores, const float* __restrict__ wvec,
    const float* __restrict__ bo,
    const unsigned short* __restrict__ W2sH, const unsigned short* __restrict__ W2sL,
    const float* __restrict__ b2, const float* __restrict__ smax,
    const float* __restrict__ dinv, const int* __restrict__ offsets,
    float* __restrict__ Y)
{
    int b = blockIdx.y;
    int off = offsets[b], len = offsets[b + 1] - off;
    int n0 = blockIdx.x * 64;
    if (n0 >= len) return;
    int nvalid = min(64, len - n0);

    int tid = threadIdx.x;
    int lane = tid & 63, w = tid >> 6;
    int ln = lane & 15, quad = lane >> 4;

    __shared__ float wsh[HID];
    __shared__ float bosh[HID];
    __shared__ float b2sh[OUT_D];

    wsh[tid] = wvec[b * HID + tid];
    bosh[tid] = bo[tid];
    if (tid < OUT_D) b2sh[tid] = b2[tid];

    float sm = smax[b], di = dinv[b];
    float p[4];
#pragma unroll
    for (int i = 0; i < 4; i++) {
        int node = 16 * i + ln;
        p[i] = (node < nvalid) ? expf(scores[off + n0 + node] - sm) * di : 0.f;
    }
    __syncthreads();

    const unsigned short* bph[2];
    const unsigned short* bpl[2];
#pragma unroll
    for (int j = 0; j < 2; j++) {
        int c = 32 * w + 16 * j + ln;
        bph[j] = W2sH + (size_t)c * 32 + quad * 8;
        bpl[j] = W2sL + (size_t)c * 32 + quad * 8;
    }

    f32x4 acc[4][2] = {};
    uint4 bhC[2], blC[2];
#pragma unroll
    for (int j = 0; j < 2; j++) {
        bhC[j] = *(const uint4*)(bph[j]);
        blC[j] = *(const uint4*)(bpl[j]);
    }

#pragma unroll
    for (int kc = 0; kc < 8; kc++) {
        uint4 bhN[2], blN[2];
        if (kc < 7) {
#pragma unroll
            for (int j = 0; j < 2; j++) {
                bhN[j] = *(const uint4*)(bph[j] + (size_t)(kc + 1) * 4096);
                blN[j] = *(const uint4*)(bpl[j] + (size_t)(kc + 1) * 4096);
            }
        }
        // z = relu(p_i * w + bo) for this lane's k-slice, hi-packed
        float4 wv0 = *(const float4*)&wsh[kc * 32 + quad * 8];
        float4 wv1 = *(const float4*)&wsh[kc * 32 + quad * 8 + 4];
        float4 bo0 = *(const float4*)&bosh[kc * 32 + quad * 8];
        float4 bo1 = *(const float4*)&bosh[kc * 32 + quad * 8 + 4];
        bf16x8 AH[4];
#pragma unroll
        for (int i = 0; i < 4; i++) {
            float4 z0, z1;
            z0.x = fmaxf(fmaf(p[i], wv0.x, bo0.x), 0.f);
            z0.y = fmaxf(fmaf(p[i], wv0.y, bo0.y), 0.f);
            z0.z = fmaxf(fmaf(p[i], wv0.z, bo0.z), 0.f);
            z0.w = fmaxf(fmaf(p[i], wv0.w, bo0.w), 0.f);
            z1.x = fmaxf(fmaf(p[i], wv1.x, bo1.x), 0.f);
            z1.y = fmaxf(fmaf(p[i], wv1.y, bo1.y), 0.f);
            z1.z = fmaxf(fmaf(p[i], wv1.z, bo1.z), 0.f);
            z1.w = fmaxf(fmaf(p[i], wv1.w, bo1.w), 0.f);
            AH[i] = pack_hi8(z0, z1);
        }
#pragma unroll
        for (int i = 0; i < 4; i++)
#pragma unroll
            for (int j = 0; j < 2; j++) {
                acc[i][j] = __builtin_amdgcn_mfma_f32_16x16x32_bf16(
                    AH[i], __builtin_bit_cast(bf16x8, bhC[j]), acc[i][j], 0, 0, 0);
                acc[i][j] = __builtin_amdgcn_mfma_f32_16x16x32_bf16(
                    AH[i], __builtin_bit_cast(bf16x8, blC[j]), acc[i][j], 0, 0, 0);
            }
        if (kc < 7) {
#pragma unroll
            for (int j = 0; j < 2; j++) { bhC[j] = bhN[j]; blC[j] = blN[j]; }
        }
    }

    // ---- epilogue: + b2, masked store ----
#pragma unroll
    for (int i = 0; i < 4; i++)
#pragma unroll
        for (int j = 0; j < 2; j++) {
            int c = 32 * w + 16 * j + ln;
            float bb = b2sh[c];
#pragma unroll
            for (int r = 0; r < 4; r++) {
                int node = 16 * i + 4 * quad + r;
                if (node < nvalid)
                    Y[(size_t)(off + n0 + node) * OUT_D + c] = acc[i][j][r] + bb;
            }
        }
}

// ---------------------------------------------------------------------------
extern "C" void kernel_launch(void* const* d_in, const int* in_sizes, int n_in,
                              void* d_out, int out_size, void* d_ws, size_t ws_size,
                              hipStream_t stream)
{
    const float* X        = (const float*)d_in[0];
    const float* text_emb = (const float*)d_in[1];
    const int*   lens     = (const int*)d_in[2];
    const float* W0       = (const float*)d_in[3];
    const float* b0       = (const float*)d_in[4];
    const float* Wq       = (const float*)d_in[5];
    const float* bq       = (const float*)d_in[6];
    const float* Wk       = (const float*)d_in[7];
    // d_in[8] = bk : softmax-invariant, unused
    const float* Wv       = (const float*)d_in[9];
    const float* bv       = (const float*)d_in[10];
    const float* Wo       = (const float*)d_in[11];
    const float* bo       = (const float*)d_in[12];
    const float* W2       = (const float*)d_in[13];
    const float* b2       = (const float*)d_in[14];
    float* Y = (float*)d_out;

    char* base = (char*)d_ws;
    size_t o = 0;
    int*   offsets = (int*)(base + o);            o += 1088;
    float* qkbuf   = (float*)(base + o);          o += 262144;
    float* wvec    = (float*)(base + o);          o += 262144;
    float* smaxb   = (float*)(base + o);          o += 1024;
    float* dinvb   = (float*)(base + o);          o += 1024;
    float* hsum    = (float*)(base + o);          o += 262144;
    float* scores  = (float*)(base + o);          o += 262144;
    unsigned short* W0sH = (unsigned short*)(base + o); o += 65536;
    unsigned short* W0sL = (unsigned short*)(base + o); o += 65536;
    unsigned short* W2sH = (unsigned short*)(base + o); o += 65536;
    unsigned short* W2sL = (unsigned short*)(base + o); o += 65536;

    k_prepA<<<259, 1024, 0, stream>>>(text_emb, Wq, bq, Wk, W0, W2, lens,
                                      qkbuf, offsets, hsum, W0sH, W0sL, W2sH, W2sL);
    k_l0_mfma<<<dim3(6, B_G), 256, 0, stream>>>(X, W0sH, W0sL, b0, qkbuf, offsets, scores, hsum);
    k_graph<<<B_G, 1024, 0, stream>>>(scores, hsum, Wv, bv, Wo, offsets, wvec, smaxb, dinvb);
    k_fin_mfma<<<dim3(6, B_G), 256, 0, stream>>>(scores, wvec, bo, W2sH, W2sL, b2, smaxb, dinvb, offsets, Y);
}